// Round 11
// baseline (208.210 us; speedup 1.0000x reference)
//
#include <hip/hip_runtime.h>
#include <math.h>

// NOTE: resubmission of the round-10 source — container-level infra failure
// (third occurrence this session: R0, R4/R5, R10), kernel never measured.
// Single-variable experiment vs R2 baseline: amdgpu_waves_per_eu(4,4).

typedef float        f32x4 __attribute__((ext_vector_type(4)));
typedef unsigned int u32x4 __attribute__((ext_vector_type(4)));

static constexpr int DIM    = 33;
static constexpr int LUT_N  = DIM * DIM * DIM;          // 35937
static constexpr int HW     = 1024 * 1024;
static constexpr int BATCH  = 8;
static constexpr long NPIX  = (long)BATCH * HW;         // 8388608
static constexpr long NTASK = NPIX / 4;                 // fallback only

static constexpr size_t LDS_BYTES = 143872;             // 128B-rounded >= LUT_N*4

// apply geometry: 256 blocks x 1024 threads == HW/4 threads exactly.
static constexpr int ABLK = 256;
static constexpr int ATHR = 1024;

// ---------------------------------------------------------------------------
// helpers
// ---------------------------------------------------------------------------
__device__ __forceinline__ f32x4 ntl4(const float* p) {
    return __builtin_nontemporal_load((const f32x4*)p);
}
__device__ __forceinline__ void nts4(float* p, f32x4 v) {
    __builtin_nontemporal_store(v, (f32x4*)p);
}
__device__ __forceinline__ float d_r(unsigned n) { return (float)(n & 1023u); }
__device__ __forceinline__ float d_g(unsigned n) { return (float)((n >> 10) & 1023u); }
__device__ __forceinline__ float d_b(unsigned n) { return (float)(n >> 20); }

// ---------------------------------------------------------------------------
// Fused single kernel — EXACT round-2 structure (best measured: 61.3 us),
// with ONE change: occupancy attribute.
//
// R7/R8/R9 evidence: __launch_bounds__(1024, 4) sets amdgpu-waves-per-eu
// min=4 with default max (8) -> the scheduler targets 8 waves/EU, shrinks
// VGPR to 40-52, and schedules as if 8 waves hide latency. But the 140 KiB
// dynamic LDS caps occupancy at 4 waves/EU (invisible to the compiler), so
// those kernels ran 78-85 us vs 61-62 us for the un-hinted R2/R6.
// amdgpu_waves_per_eu(4,4) pins BOTH ends: VGPR budget 128, scheduler
// latency model = 4 waves = reality.
// ---------------------------------------------------------------------------
__global__ __launch_bounds__(1024)
__attribute__((amdgpu_waves_per_eu(4, 4)))
void lut_fused(
    const float* __restrict__ x, const float* __restrict__ lut,
    float* __restrict__ out) {
    extern __shared__ unsigned sl[];
    const int t = threadIdx.x;

    // ---- stage A: block-wide min/max over all 3*LUT_N floats ----
    float vmin = 1e30f, vmax = -1e30f;
    {
        const f32x4* l4 = (const f32x4*)lut;        // base is 16B-aligned
        const int NV = (3 * LUT_N) / 4;             // 26952 full float4s
#pragma unroll 4
        for (int i = t; i < NV; i += 1024) {
            f32x4 v = l4[i];
            vmin = fminf(vmin, fminf(fminf(v[0], v[1]), fminf(v[2], v[3])));
            vmax = fmaxf(vmax, fmaxf(fmaxf(v[0], v[1]), fmaxf(v[2], v[3])));
        }
        if (t < 3) {                                 // tail elems 107808..107810
            float v = lut[NV * 4 + t];
            vmin = fminf(vmin, v);
            vmax = fmaxf(vmax, v);
        }
    }
    // wave reduce (64 lanes), then cross-wave via 32 floats of LDS
#pragma unroll
    for (int off = 32; off > 0; off >>= 1) {
        vmin = fminf(vmin, __shfl_down(vmin, off));
        vmax = fmaxf(vmax, __shfl_down(vmax, off));
    }
    float* sf = (float*)sl;
    if ((t & 63) == 0) { sf[t >> 6] = vmin; sf[16 + (t >> 6)] = vmax; }
    __syncthreads();
    float mn = sf[0], mx = sf[16];
#pragma unroll
    for (int k = 1; k < 16; ++k) {
        mn = fminf(mn, sf[k]);
        mx = fmaxf(mx, sf[16 + k]);
    }
    __syncthreads();  // everyone holds mn/mx in registers; sl may be reused

    float range = mx - mn;
    if (range < 1e-20f) range = 1e-20f;
    const float qscale = 1023.0f / range;
    const float inv    = range * (1.0f / 1023.0f);

    // ---- stage B: quantize LUT into LDS (coalesced scalar, L2-hot) ----
    for (int i = t; i < LUT_N; i += 1024) {
        float r = lut[i], g = lut[LUT_N + i], b = lut[2 * LUT_N + i];
        unsigned qr = (unsigned)__float2int_rn((r - mn) * qscale);
        unsigned qg = (unsigned)__float2int_rn((g - mn) * qscale);
        unsigned qb = (unsigned)__float2int_rn((b - mn) * qscale);
        sl[i] = qr | (qg << 10) | (qb << 20);
    }
    __syncthreads();

    // ---- stage C: apply ----
    const int gtid = blockIdx.x * ATHR + t;          // [0, 2^18)
    const size_t hw4 = (size_t)gtid * 4;             // [0, HW)
    const float* xp = x + hw4;
    float*       op = out + hw4;

    // prologue: image 0
    f32x4 rc = ntl4(xp);
    f32x4 gc = ntl4(xp + HW);
    f32x4 bc = ntl4(xp + 2 * (size_t)HW);

    for (int it = 0; it < BATCH; ++it) {
        // issue next image's loads early (hidden under this image's compute)
        f32x4 rn = {}, gn = {}, bn = {};
        if (it != BATCH - 1) {
            const float* xn = xp + (size_t)(it + 1) * (3 * (size_t)HW);
            rn = ntl4(xn);
            gn = ntl4(xn + HW);
            bn = ntl4(xn + 2 * (size_t)HW);
        }

        // phase 1: indices + all 32 LDS gathers for the 4 pixels
        unsigned n[4][8];
        float fr[4], fg[4], fb[4];
#pragma unroll
        for (int i = 0; i < 4; ++i) {
            const float scale = (float)(DIM - 1);
            float rs = rc[i] * scale, gs = gc[i] * scale, bs = bc[i] * scale;
            int ir = (int)rs; ir = ir < 0 ? 0 : (ir > DIM - 2 ? DIM - 2 : ir);
            int ig = (int)gs; ig = ig < 0 ? 0 : (ig > DIM - 2 ? DIM - 2 : ig);
            int ib = (int)bs; ib = ib < 0 ? 0 : (ib > DIM - 2 ? DIM - 2 : ib);
            fr[i] = rs - (float)ir;
            fg[i] = gs - (float)ig;
            fb[i] = bs - (float)ib;
            int s = ib * (DIM * DIM) + ig * DIM + ir;
            n[i][0] = sl[s];                     n[i][1] = sl[s + 1];
            n[i][2] = sl[s + DIM];               n[i][3] = sl[s + DIM + 1];
            n[i][4] = sl[s + DIM * DIM];         n[i][5] = sl[s + DIM * DIM + 1];
            n[i][6] = sl[s + DIM * DIM + DIM];   n[i][7] = sl[s + DIM * DIM + DIM + 1];
        }

        // phase 2: decode + weighted sum (weights shared across 3 channels)
        f32x4 orv, ogv, obv;
#pragma unroll
        for (int i = 0; i < 4; ++i) {
            float frc = 1.0f - fr[i], fgc = 1.0f - fg[i], fbc = 1.0f - fb[i];
            float w00 = fbc * fgc, w01 = fbc * fg[i];
            float w10 = fb[i] * fgc, w11 = fb[i] * fg[i];
            float u0 = w00 * frc, u1 = w00 * fr[i];
            float u2 = w01 * frc, u3 = w01 * fr[i];
            float u4 = w10 * frc, u5 = w10 * fr[i];
            float u6 = w11 * frc, u7 = w11 * fr[i];

            float qr = u0 * d_r(n[i][0]);
            qr = fmaf(u1, d_r(n[i][1]), qr);
            qr = fmaf(u2, d_r(n[i][2]), qr);
            qr = fmaf(u3, d_r(n[i][3]), qr);
            qr = fmaf(u4, d_r(n[i][4]), qr);
            qr = fmaf(u5, d_r(n[i][5]), qr);
            qr = fmaf(u6, d_r(n[i][6]), qr);
            qr = fmaf(u7, d_r(n[i][7]), qr);

            float qg = u0 * d_g(n[i][0]);
            qg = fmaf(u1, d_g(n[i][1]), qg);
            qg = fmaf(u2, d_g(n[i][2]), qg);
            qg = fmaf(u3, d_g(n[i][3]), qg);
            qg = fmaf(u4, d_g(n[i][4]), qg);
            qg = fmaf(u5, d_g(n[i][5]), qg);
            qg = fmaf(u6, d_g(n[i][6]), qg);
            qg = fmaf(u7, d_g(n[i][7]), qg);

            float qb = u0 * d_b(n[i][0]);
            qb = fmaf(u1, d_b(n[i][1]), qb);
            qb = fmaf(u2, d_b(n[i][2]), qb);
            qb = fmaf(u3, d_b(n[i][3]), qb);
            qb = fmaf(u4, d_b(n[i][4]), qb);
            qb = fmaf(u5, d_b(n[i][5]), qb);
            qb = fmaf(u6, d_b(n[i][6]), qb);
            qb = fmaf(u7, d_b(n[i][7]), qb);

            orv[i] = fmaf(qr, inv, mn);
            ogv[i] = fmaf(qg, inv, mn);
            obv[i] = fmaf(qb, inv, mn);
        }

        float* o = op + (size_t)it * (3 * (size_t)HW);
        nts4(o, orv);
        nts4(o + HW, ogv);
        nts4(o + 2 * (size_t)HW, obv);

        rc = rn; gc = gn; bc = bn;
    }
}

// ---------------------------------------------------------------------------
// Fallback: direct SoA gathers, exact fp32 (safety net; not dispatched).
// ---------------------------------------------------------------------------
__global__ __launch_bounds__(256) void lut_apply_soa(
    const float* __restrict__ x, const float* __restrict__ lut,
    float* __restrict__ out) {
    long t = (long)blockIdx.x * 256 + threadIdx.x;
    long p = t * 4;
    int  b  = (int)(p >> 20);
    int  hw = (int)(p & (HW - 1));
    size_t base = (size_t)b * (3 * (size_t)HW) + (size_t)hw;

    float4 rv = *(const float4*)(x + base);
    float4 gv = *(const float4*)(x + base + (size_t)HW);
    float4 bv = *(const float4*)(x + base + 2 * (size_t)HW);

    float rr[4] = {rv.x, rv.y, rv.z, rv.w};
    float gg[4] = {gv.x, gv.y, gv.z, gv.w};
    float bb[4] = {bv.x, bv.y, bv.z, bv.w};
    float orr[4], org[4], orb[4];

#pragma unroll
    for (int i = 0; i < 4; ++i) {
        const float scale = (float)(DIM - 1);
        float rs = rr[i] * scale, gs = gg[i] * scale, bs = bb[i] * scale;
        int ir = (int)floorf(rs); ir = ir < 0 ? 0 : (ir > DIM - 2 ? DIM - 2 : ir);
        int ig = (int)floorf(gs); ig = ig < 0 ? 0 : (ig > DIM - 2 ? DIM - 2 : ig);
        int ib = (int)floorf(bs); ib = ib < 0 ? 0 : (ib > DIM - 2 ? DIM - 2 : ib);
        float fr = rs - (float)ir, fg = gs - (float)ig, fb = bs - (float)ib;
        int base_i = (ib * DIM + ig) * DIM + ir;
        float acc[3] = {0.f, 0.f, 0.f};
#pragma unroll
        for (int db = 0; db < 2; ++db) {
            float wb = db ? fb : 1.f - fb;
#pragma unroll
            for (int dg = 0; dg < 2; ++dg) {
                float wg = dg ? fg : 1.f - fg;
#pragma unroll
                for (int dr = 0; dr < 2; ++dr) {
                    float wr = dr ? fr : 1.f - fr;
                    int idx = base_i + (db * DIM + dg) * DIM + dr;
                    float w = wb * wg * wr;
                    acc[0] = fmaf(w, lut[idx], acc[0]);
                    acc[1] = fmaf(w, lut[LUT_N + idx], acc[1]);
                    acc[2] = fmaf(w, lut[2 * LUT_N + idx], acc[2]);
                }
            }
        }
        orr[i] = acc[0]; org[i] = acc[1]; orb[i] = acc[2];
    }

    *(float4*)(out + base)                  = make_float4(orr[0], orr[1], orr[2], orr[3]);
    *(float4*)(out + base + (size_t)HW)     = make_float4(org[0], org[1], org[2], org[3]);
    *(float4*)(out + base + 2 * (size_t)HW) = make_float4(orb[0], orb[1], orb[2], orb[3]);
}

extern "C" void kernel_launch(void* const* d_in, const int* in_sizes, int n_in,
                              void* d_out, int out_size, void* d_ws, size_t ws_size,
                              hipStream_t stream) {
    const float* lut = (const float*)d_in[0];
    const float* x   = (const float*)d_in[1];
    if (n_in >= 2 && in_sizes[0] > in_sizes[1]) {  // defensive: order swapped
        lut = (const float*)d_in[1];
        x   = (const float*)d_in[0];
    }
    float* out = (float*)d_out;
    (void)d_ws; (void)ws_size;

    // Allow >64KB dynamic LDS (gfx950 has 160 KiB). Host-side attr set,
    // idempotent, graph-capture safe.
    (void)hipFuncSetAttribute((const void*)lut_fused,
                              hipFuncAttributeMaxDynamicSharedMemorySize,
                              (int)LDS_BYTES);
    lut_fused<<<ABLK, ATHR, LDS_BYTES, stream>>>(x, lut, out);
}